// Round 13
// baseline (70.282 us; speedup 1.0000x reference)
//
#include <hip/hip_runtime.h>

#define NB    32
#define LSEQ  4096
#define DM    512

typedef float f32x4 __attribute__((ext_vector_type(4)));

// workspace layout (floats): gates[5*512] then P[5][NB][2052]
#define GATES_OFF 0
#define P_OFF     (5 * DM)
#define P_STRIDE  2052

// P-chunking: 65 chunks of 32 per batch covers 2051
#define CH_PER_B    65
#define NTASK       (NB * CH_PER_B)          // 2080 wave-tasks
#define PROD_BLOCKS ((NTASK + 3) / 4)        // 520
#define GATE_BLOCKS 128                      // 512 channels / 4 waves

// db4 decomposition low-pass; DEC_HI[k] = (-1)^(k+1) * DEC_LO[7-k]
__device__ __constant__ float c_DL[8] = {
    -0.010597401784997278f,  0.032883011666982945f,  0.030841381835986965f,
    -0.18703481171888114f,  -0.02798376941698385f,   0.6308807679295904f,
     0.7148465705525415f,    0.23037781330885523f};
__device__ __constant__ float c_DH[8] = {
    -0.23037781330885523f,   0.7148465705525415f,   -0.6308807679295904f,
    -0.02798376941698385f,   0.18703481171888114f,   0.030841381835986965f,
    -0.032883011666982945f, -0.010597401784997278f};

// per-wave cone buffer offsets (floats); sizes have slack over derived maxima
#define O_XW   0      // 272 needed (tx span <= 266)
#define O_LO1  280    // 130
#define O_LO2  424    // 62
#define O_LO3  496    // 28
#define O_HI1  536    // 32
#define O_H2   576    // 19
#define O_H3   604    // 14
#define O_L4   624    // 11
#define O_H4   640    // 11
#define O_A    656    // 14
#define O_A4   676    // 14
#define O_A3   696    // 19
#define O_B    724    // 19
#define O_B4   752    // 19
#define O_P0   772    // 32
#define O_P2   812    // 32
#define O_P3   852    // 32
#define O_P4   892    // 32 -> end 924
#define CONE_STRIDE 928

__device__ __forceinline__ int imin(int a, int b) { return a < b ? a : b; }
__device__ __forceinline__ int imax(int a, int b) { return a > b ? a : b; }

__device__ __forceinline__ int reflect_idx(int i, int N) {
    if (i < 0)  i = -1 - i;
    if (i >= N) i = 2 * N - 1 - i;
    return i;
}

// Wave-local forward DWT over [d_lo, d_hi], lane-strided (stride 64).
// No barriers: intra-wave LDS ordering via automatic lgkmcnt waits.
template <bool HI>
__device__ void fwd_range_w(const float* __restrict__ src, int src_lo, int Nsrc,
                            float* __restrict__ dst, int d_lo, int d_hi, int lane) {
    for (int t = d_lo + lane; t <= d_hi; t += 64) {
        int base = 2 * t - 6;
        float acc = 0.f;
#pragma unroll
        for (int k = 0; k < 8; ++k) {
            float xv = src[reflect_idx(base + k, Nsrc) - src_lo];
            acc = fmaf(xv, HI ? c_DH[7 - k] : c_DL[7 - k], acc);
        }
        dst[t - d_lo] = acc;
    }
}

// Wave-local inverse DWT step over [y_lo, y_hi], lane-strided.
template <bool HI>
__device__ void inv_range_w(const float* __restrict__ c, int c_lo,
                            float* __restrict__ y, int y_lo, int y_hi, int lane) {
    for (int t = y_lo + lane; t <= y_hi; t += 64) {
        int base = (t >> 1) - c_lo;
        int odd = t & 1;
        float f0 = odd ? (HI ? c_DH[0] : c_DL[0]) : (HI ? c_DH[1] : c_DL[1]);
        float f1 = odd ? (HI ? c_DH[2] : c_DL[2]) : (HI ? c_DH[3] : c_DL[3]);
        float f2 = odd ? (HI ? c_DH[4] : c_DL[4]) : (HI ? c_DH[5] : c_DL[5]);
        float f3 = odd ? (HI ? c_DH[6] : c_DL[6]) : (HI ? c_DH[7] : c_DL[7]);
        float acc = c[base] * f0;
        acc = fmaf(c[base + 1], f1, acc);
        acc = fmaf(c[base + 2], f2, acc);
        acc = fmaf(c[base + 3], f3, acc);
        y[t - y_lo] = acc;
    }
}

// Blocks 0..519: per-wave barrier-free P-cones. Each wave owns one 32-wide
// chunk [p0, p1] of one batch's 2051-long P level and computes all 5 planes
// (P0 = LO^3(L4), P1 = H1, P2 = HI(H2), P3 = LO(HI(H3)), P4 = LO^2(HI(H4)))
// from a windowed recomputation of the forward transform. Exact partition:
// every P value written exactly once.
// Blocks 520..647: gates (wave-per-channel coalesced GEMV).
__global__ __launch_bounds__(256, 4) void prod_gates_kernel(
    const float* __restrict__ x, const float* __restrict__ proj_w,
    const float* __restrict__ proj_b, const float* __restrict__ scale_emb,
    const float* __restrict__ gate_w, const float* __restrict__ gate_b,
    float* __restrict__ ws) {
    int wid = threadIdx.x >> 6;
    int lane = threadIdx.x & 63;

    if (blockIdx.x >= PROD_BLOCKS) {
        // ---- gates: one wave per channel ----
        int c = (blockIdx.x - PROD_BLOCKS) * 4 + wid;   // 0..511
        const float4* rg = (const float4*)(gate_w + (size_t)c * DM) + lane * 2;
        const float4* rv = (const float4*)(gate_w + (size_t)(c + DM) * DM) + lane * 2;
        float4 a0 = rg[0], a1 = rg[1];
        float4 b0 = rv[0], b1 = rv[1];
        float gacc[5], vacc[5];
#pragma unroll
        for (int j = 0; j < 5; ++j) {
            const float4* sj = (const float4*)(scale_emb + (size_t)j * DM) + lane * 2;
            float4 s0 = sj[0], s1 = sj[1];
            float ga;
            ga = s0.x * a0.x;            ga = fmaf(s0.y, a0.y, ga);
            ga = fmaf(s0.z, a0.z, ga);   ga = fmaf(s0.w, a0.w, ga);
            ga = fmaf(s1.x, a1.x, ga);   ga = fmaf(s1.y, a1.y, ga);
            ga = fmaf(s1.z, a1.z, ga);   ga = fmaf(s1.w, a1.w, ga);
            float va;
            va = s0.x * b0.x;            va = fmaf(s0.y, b0.y, va);
            va = fmaf(s0.z, b0.z, va);   va = fmaf(s0.w, b0.w, va);
            va = fmaf(s1.x, b1.x, va);   va = fmaf(s1.y, b1.y, va);
            va = fmaf(s1.z, b1.z, va);   va = fmaf(s1.w, b1.w, va);
            gacc[j] = ga;
            vacc[j] = va;
        }
#pragma unroll
        for (int j = 0; j < 5; ++j) {
#pragma unroll
            for (int off = 32; off > 0; off >>= 1) {
                gacc[j] += __shfl_xor(gacc[j], off, 64);
                vacc[j] += __shfl_xor(vacc[j], off, 64);
            }
        }
        if (lane == 0) {
            float bg = gate_b[c], bv = gate_b[DM + c];
#pragma unroll
            for (int j = 0; j < 5; ++j) {
                float g = gacc[j] + bg;
                float v = vacc[j] + bv;
                float sg = 1.f / (1.f + expf(-g));
                ws[GATES_OFF + j * DM + c] = sg * tanhf(v);
            }
        }
        return;
    }

    __shared__ float CB[4][CONE_STRIDE];   // ~14.5 KB
    int task = blockIdx.x * 4 + wid;
    if (task >= NTASK) return;
    int b  = task / CH_PER_B;
    int cc = task % CH_PER_B;
    int p0 = cc * 32;
    int p1 = imin(p0 + 31, 2050);

    // ---- dependency-cone windows for [p0, p1] ----
    int b0 = p0 >> 1,  b1 = (p1 >> 1) + 3;                // 1029 level
    int a0 = b0 >> 1,  a1 = (b1 >> 1) + 3;                // 518 level
    int w0 = a0 >> 1,  w1 = (a1 >> 1) + 3;                // 262 level
    int t3lo = imax(imin(imin(2 * w0 - 6, a0), 517), 0);
    int t3hi = imin(imax(imax(2 * w1 + 1, a1), 0), 517);
    int t2lo = imax(imin(2 * t3lo - 6, 2 * a0 - 6), 0);
    int t2hi = imin(imax(2 * t3hi + 1, 2 * a1 + 1), 1028);
    int t1lo = imax(imin(2 * t2lo - 6, 2 * b0 - 6), 0);
    int t1hi = imin(imax(2 * t2hi + 1, 2 * b1 + 1), 2050);
    int txlo = imax(imin(2 * t1lo - 6, 2 * p0 - 6), 0);
    int txhi = imin(imax(2 * t1hi + 1, 2 * p1 + 1), 4095);

    float* W = CB[wid];

    // ---- projection over this wave's x window ----
    {
        float w[8];
#pragma unroll
        for (int k = 0; k < 8; ++k) w[k] = proj_w[k];
        float pb = proj_b[0];
        const float* xb = x + (size_t)b * LSEQ * 8;
        for (int i = txlo + lane; i <= txhi; i += 64) {
            const float4* xv = (const float4*)(xb + (size_t)i * 8);
            float4 q0 = xv[0], q1 = xv[1];
            float acc = pb;
            acc = fmaf(q0.x, w[0], acc); acc = fmaf(q0.y, w[1], acc);
            acc = fmaf(q0.z, w[2], acc); acc = fmaf(q0.w, w[3], acc);
            acc = fmaf(q1.x, w[4], acc); acc = fmaf(q1.y, w[5], acc);
            acc = fmaf(q1.z, w[6], acc); acc = fmaf(q1.w, w[7], acc);
            W[O_XW + i - txlo] = acc;
        }
    }

    // ---- forward levels (wave-private, barrier-free) ----
    fwd_range_w<false>(W + O_XW, txlo, 4096, W + O_LO1, t1lo, t1hi, lane);
    fwd_range_w<true >(W + O_XW, txlo, 4096, W + O_HI1, p0, p1, lane);   // P1
    fwd_range_w<false>(W + O_LO1, t1lo, 2051, W + O_LO2, t2lo, t2hi, lane);
    fwd_range_w<true >(W + O_LO1, t1lo, 2051, W + O_H2, b0, b1, lane);
    fwd_range_w<false>(W + O_LO2, t2lo, 1029, W + O_LO3, t3lo, t3hi, lane);
    fwd_range_w<true >(W + O_LO2, t2lo, 1029, W + O_H3, a0, a1, lane);
    fwd_range_w<false>(W + O_LO3, t3lo, 518, W + O_L4, w0, w1, lane);
    fwd_range_w<true >(W + O_LO3, t3lo, 518, W + O_H4, w0, w1, lane);

    // ---- inverse chains to the P (2051) level ----
    inv_range_w<false>(W + O_L4, w0, W + O_A,  a0, a1, lane);            // chain0
    inv_range_w<true >(W + O_H4, w0, W + O_A4, a0, a1, lane);            // chain4
    inv_range_w<true >(W + O_H3, a0, W + O_A3, b0, b1, lane);            // chain3
    inv_range_w<true >(W + O_H2, b0, W + O_P2, p0, p1, lane);            // P2
    inv_range_w<false>(W + O_A,  a0, W + O_B,  b0, b1, lane);
    inv_range_w<false>(W + O_A4, a0, W + O_B4, b0, b1, lane);
    inv_range_w<false>(W + O_A3, b0, W + O_P3, p0, p1, lane);            // P3
    inv_range_w<false>(W + O_B,  b0, W + O_P0, p0, p1, lane);            // P0
    inv_range_w<false>(W + O_B4, b0, W + O_P4, p0, p1, lane);            // P4

    // ---- write the 5 P planes for this chunk ----
    float* P = ws + P_OFF;
    for (int t = p0 + lane; t <= p1; t += 64) {
        int o = t - p0;
        P[(size_t)(0 * NB + b) * P_STRIDE + t] = W[O_P0 + o];
        P[(size_t)(1 * NB + b) * P_STRIDE + t] = W[O_HI1 + o];
        P[(size_t)(2 * NB + b) * P_STRIDE + t] = W[O_P2 + o];
        P[(size_t)(3 * NB + b) * P_STRIDE + t] = W[O_P3 + o];
        P[(size_t)(4 * NB + b) * P_STRIDE + t] = W[O_P4 + o];
    }
}

// pe[b,l,c] = sum_j gates[j][c] * s_j[l], with the LAST inverse level inlined:
// s_j[l] = sum_i P_j[b][(l>>1)+i] * F_j[2i+1-(l&1)], F_j = DH if j==1 else DL.
// (R6's proven ~44 us shape.) Output stores are nontemporal.
__global__ __launch_bounds__(256) void expand_kernel(
    const float* __restrict__ ws, float* __restrict__ out) {
    const float* gates = ws + GATES_OFF;
    __shared__ float gl[5 * DM];
    __shared__ float sArr[5 * 32];
    for (int i = threadIdx.x; i < 5 * DM / 4; i += 256)
        ((f32x4*)gl)[i] = ((const f32x4*)gates)[i];

    int bid = blockIdx.x;
    int b  = bid >> 7;            // 128 blocks per batch
    int l0 = (bid & 127) * 32;

    int t = threadIdx.x;
    if (t < 160) {
        int j = t >> 5, r = t & 31;
        int l = l0 + r;
        int base = l >> 1;
        int odd = l & 1;
        bool hi = (j == 1);
        const float* Pj = ws + P_OFF + (size_t)(j * NB + b) * P_STRIDE;
        float f0 = odd ? (hi ? c_DH[0] : c_DL[0]) : (hi ? c_DH[1] : c_DL[1]);
        float f1 = odd ? (hi ? c_DH[2] : c_DL[2]) : (hi ? c_DH[3] : c_DL[3]);
        float f2 = odd ? (hi ? c_DH[4] : c_DL[4]) : (hi ? c_DH[5] : c_DL[5]);
        float f3 = odd ? (hi ? c_DH[6] : c_DL[6]) : (hi ? c_DH[7] : c_DL[7]);
        float acc = Pj[base] * f0;
        acc = fmaf(Pj[base + 1], f1, acc);
        acc = fmaf(Pj[base + 2], f2, acc);
        acc = fmaf(Pj[base + 3], f3, acc);
        sArr[t] = acc;
    }
    __syncthreads();

    int half = threadIdx.x >> 7;       // 0/1: which row of the pair
    int c4 = threadIdx.x & 127;        // float4 index over 512 channels
    f32x4 g0 = ((const f32x4*)(gl + 0 * DM))[c4];
    f32x4 g1 = ((const f32x4*)(gl + 1 * DM))[c4];
    f32x4 g2 = ((const f32x4*)(gl + 2 * DM))[c4];
    f32x4 g3 = ((const f32x4*)(gl + 3 * DM))[c4];
    f32x4 g4 = ((const f32x4*)(gl + 4 * DM))[c4];

#pragma unroll 4
    for (int r = 0; r < 16; ++r) {
        int rr = r * 2 + half;
        int row = bid * 32 + rr;
        float s0 = sArr[rr];
        float s1 = sArr[32 + rr];
        float s2 = sArr[64 + rr];
        float s3 = sArr[96 + rr];
        float s4 = sArr[128 + rr];
        f32x4 acc;
        acc.x = fmaf(s4, g4.x, fmaf(s3, g3.x, fmaf(s2, g2.x, fmaf(s1, g1.x, s0 * g0.x))));
        acc.y = fmaf(s4, g4.y, fmaf(s3, g3.y, fmaf(s2, g2.y, fmaf(s1, g1.y, s0 * g0.y))));
        acc.z = fmaf(s4, g4.z, fmaf(s3, g3.z, fmaf(s2, g2.z, fmaf(s1, g1.z, s0 * g0.z))));
        acc.w = fmaf(s4, g4.w, fmaf(s3, g3.w, fmaf(s2, g2.w, fmaf(s1, g1.w, s0 * g0.w))));
        __builtin_nontemporal_store(acc, (f32x4*)out + (size_t)row * (DM / 4) + c4);
    }
}

extern "C" void kernel_launch(void* const* d_in, const int* in_sizes, int n_in,
                              void* d_out, int out_size, void* d_ws, size_t ws_size,
                              hipStream_t stream) {
    const float* x         = (const float*)d_in[0];
    const float* proj_w    = (const float*)d_in[1];
    const float* proj_b    = (const float*)d_in[2];
    const float* scale_emb = (const float*)d_in[3];
    const float* gate_w    = (const float*)d_in[4];
    const float* gate_b    = (const float*)d_in[5];
    float* out = (float*)d_out;
    float* ws  = (float*)d_ws;

    prod_gates_kernel<<<PROD_BLOCKS + GATE_BLOCKS, 256, 0, stream>>>(
        x, proj_w, proj_b, scale_emb, gate_w, gate_b, ws);
    expand_kernel<<<(NB * LSEQ) / 32, 256, 0, stream>>>(ws, out);
}

// Round 14
// 66.239 us; speedup vs baseline: 1.0610x; 1.0610x over previous
//
#include <hip/hip_runtime.h>

#define NB    32
#define LSEQ  4096
#define DM    512
#define BROWS 256                   // rows per block
#define NBLK  (NB * LSEQ / BROWS)   // 512 blocks

typedef float f32x4 __attribute__((ext_vector_type(4)));

// db4 decomposition low-pass; DEC_HI[k] = (-1)^(k+1) * DEC_LO[7-k]
__device__ __constant__ float c_DL[8] = {
    -0.010597401784997278f,  0.032883011666982945f,  0.030841381835986965f,
    -0.18703481171888114f,  -0.02798376941698385f,   0.6308807679295904f,
     0.7148465705525415f,    0.23037781330885523f};
__device__ __constant__ float c_DH[8] = {
    -0.23037781330885523f,   0.7148465705525415f,   -0.6308807679295904f,
    -0.02798376941698385f,   0.18703481171888114f,   0.030841381835986965f,
    -0.032883011666982945f, -0.010597401784997278f};

__device__ __forceinline__ int imin(int a, int b) { return a < b ? a : b; }
__device__ __forceinline__ int imax(int a, int b) { return a > b ? a : b; }

__device__ __forceinline__ int reflect_idx(int i, int N) {
    if (i < 0)  i = -1 - i;
    if (i >= N) i = 2 * N - 1 - i;
    return i;
}

// Forward DWT (one filter) over output window [d_lo, d_hi]; src is a window
// array covering all (reflected) reads. y[t] = sum_k src[ref(2t-6+k)]*F[7-k].
template <bool HI>
__device__ void fwd_range(const float* __restrict__ src, int src_lo, int Nsrc,
                          float* __restrict__ dst, int d_lo, int d_hi) {
    for (int t = d_lo + (int)threadIdx.x; t <= d_hi; t += 256) {
        int base = 2 * t - 6;
        float acc = 0.f;
#pragma unroll
        for (int k = 0; k < 8; ++k) {
            float xv = src[reflect_idx(base + k, Nsrc) - src_lo];
            acc = fmaf(xv, HI ? c_DH[7 - k] : c_DL[7 - k], acc);
        }
        dst[t - d_lo] = acc;
    }
}

// Inverse DWT step over output window [y_lo, y_hi]; c is a window array.
// y[t] = sum_{i=0..3} c[(t>>1)+i] * F[2i+1-(t&1)]  (always in-range).
template <bool HI>
__device__ void inv_range(const float* __restrict__ c, int c_lo,
                          float* __restrict__ y, int y_lo, int y_hi) {
    for (int t = y_lo + (int)threadIdx.x; t <= y_hi; t += 256) {
        int base = (t >> 1) - c_lo;
        int odd = t & 1;
        float f0 = odd ? (HI ? c_DH[0] : c_DL[0]) : (HI ? c_DH[1] : c_DL[1]);
        float f1 = odd ? (HI ? c_DH[2] : c_DL[2]) : (HI ? c_DH[3] : c_DL[3]);
        float f2 = odd ? (HI ? c_DH[4] : c_DL[4]) : (HI ? c_DH[5] : c_DL[5]);
        float f3 = odd ? (HI ? c_DH[6] : c_DL[6]) : (HI ? c_DH[7] : c_DL[7]);
        float acc = c[base] * f0;
        acc = fmaf(c[base + 1], f1, acc);
        acc = fmaf(c[base + 2], f2, acc);
        acc = fmaf(c[base + 3], f3, acc);
        y[t - y_lo] = acc;
    }
}

// One wave per channel c: coalesced rows gw[c], gw[c+512]; 5 g/v dots;
// shuffle-reduce; lane 0 writes gates[j][c] = sigmoid(g)*tanh(v).
__global__ __launch_bounds__(1024) void gates_kernel(
    const float* __restrict__ scale_emb, const float* __restrict__ gate_w,
    const float* __restrict__ gate_b, float* __restrict__ gates) {
    int lane = threadIdx.x & 63;
    int c = blockIdx.x * 16 + (threadIdx.x >> 6);
    const float4* rg = (const float4*)(gate_w + (size_t)c * DM) + lane * 2;
    const float4* rv = (const float4*)(gate_w + (size_t)(c + DM) * DM) + lane * 2;
    float4 a0 = rg[0], a1 = rg[1];
    float4 b0 = rv[0], b1 = rv[1];
    float gacc[5], vacc[5];
#pragma unroll
    for (int j = 0; j < 5; ++j) {
        const float4* sj = (const float4*)(scale_emb + (size_t)j * DM) + lane * 2;
        float4 s0 = sj[0], s1 = sj[1];
        float ga;
        ga = s0.x * a0.x;            ga = fmaf(s0.y, a0.y, ga);
        ga = fmaf(s0.z, a0.z, ga);   ga = fmaf(s0.w, a0.w, ga);
        ga = fmaf(s1.x, a1.x, ga);   ga = fmaf(s1.y, a1.y, ga);
        ga = fmaf(s1.z, a1.z, ga);   ga = fmaf(s1.w, a1.w, ga);
        float va;
        va = s0.x * b0.x;            va = fmaf(s0.y, b0.y, va);
        va = fmaf(s0.z, b0.z, va);   va = fmaf(s0.w, b0.w, va);
        va = fmaf(s1.x, b1.x, va);   va = fmaf(s1.y, b1.y, va);
        va = fmaf(s1.z, b1.z, va);   va = fmaf(s1.w, b1.w, va);
        gacc[j] = ga;
        vacc[j] = va;
    }
#pragma unroll
    for (int j = 0; j < 5; ++j) {
#pragma unroll
        for (int off = 32; off > 0; off >>= 1) {
            gacc[j] += __shfl_xor(gacc[j], off, 64);
            vacc[j] += __shfl_xor(vacc[j], off, 64);
        }
    }
    if (lane == 0) {
        float bg = gate_b[c], bv = gate_b[DM + c];
#pragma unroll
        for (int j = 0; j < 5; ++j) {
            float g = gacc[j] + bg;
            float v = vacc[j] + bv;
            float sg = 1.f / (1.f + expf(-g));
            gates[j * DM + c] = sg * tanhf(v);
        }
    }
}

// Fused cone kernel, 256 rows/block: the fixed ~220-element cone overhead is
// amortized over 4x more rows than R8 (total cone work / grid: 2.6x less).
// Then rank-5 expansion with NT float4 stores. Math identical to reference.
__global__ __launch_bounds__(256) void fused_kernel(
    const float* __restrict__ x, const float* __restrict__ proj_w,
    const float* __restrict__ proj_b, const float* __restrict__ gates,
    float* __restrict__ out) {
    __shared__ float GL[5 * DM];
    __shared__ float XW[456];
    __shared__ float LO1[232], LO2[120], LO3[64];
    __shared__ float HI1[144], H2W[80], H3W[48], L4W[32], H4W[32];
    __shared__ float AW[48], A4W[48], A3W[80], BW[80], B4W[80];
    __shared__ float P0W[144], P2W[144], P3W[144], P4W[144];
    __shared__ float SJ[5 * BROWS];

    int bid = blockIdx.x;
    int b  = bid >> 4;               // 16 chunks per batch
    int l0 = (bid & 15) * BROWS;

    // ---- dependency-cone windows (uniform scalar math) ----
    int p0 = l0 >> 1,  p1 = ((l0 + BROWS - 1) >> 1) + 3;  // P level (2051)
    int b0 = p0 >> 1,  b1 = (p1 >> 1) + 3;                // 1029 level
    int a0 = b0 >> 1,  a1 = (b1 >> 1) + 3;                // 518 level
    int w0 = a0 >> 1,  w1 = (a1 >> 1) + 3;                // 262 level
    int t3lo = imax(imin(imin(2 * w0 - 6, a0), 517), 0);
    int t3hi = imin(imax(imax(2 * w1 + 1, a1), 0), 517);
    int t2lo = imax(imin(2 * t3lo - 6, 2 * a0 - 6), 0);
    int t2hi = imin(imax(2 * t3hi + 1, 2 * a1 + 1), 1028);
    int t1lo = imax(imin(2 * t2lo - 6, 2 * b0 - 6), 0);
    int t1hi = imin(imax(2 * t2hi + 1, 2 * b1 + 1), 2050);
    int txlo = imax(imin(2 * t1lo - 6, 2 * p0 - 6), 0);
    int txhi = imin(imax(2 * t1hi + 1, 2 * p1 + 1), 4095);

    // ---- stage 1: gates -> LDS, projection over x window ----
    for (int i = threadIdx.x; i < 5 * DM / 4; i += 256)
        ((f32x4*)GL)[i] = ((const f32x4*)gates)[i];
    float w[8];
#pragma unroll
    for (int k = 0; k < 8; ++k) w[k] = proj_w[k];
    float pb = proj_b[0];
    const float* xb = x + (size_t)b * LSEQ * 8;
    for (int i = txlo + (int)threadIdx.x; i <= txhi; i += 256) {
        const float4* xv = (const float4*)(xb + (size_t)i * 8);
        float4 q0 = xv[0], q1 = xv[1];
        float acc = pb;
        acc = fmaf(q0.x, w[0], acc); acc = fmaf(q0.y, w[1], acc);
        acc = fmaf(q0.z, w[2], acc); acc = fmaf(q0.w, w[3], acc);
        acc = fmaf(q1.x, w[4], acc); acc = fmaf(q1.y, w[5], acc);
        acc = fmaf(q1.z, w[6], acc); acc = fmaf(q1.w, w[7], acc);
        XW[i - txlo] = acc;
    }
    __syncthreads();

    // ---- forward levels ----
    fwd_range<false>(XW, txlo, 4096, LO1, t1lo, t1hi);
    fwd_range<true >(XW, txlo, 4096, HI1, p0, p1);        // P1 = h1
    __syncthreads();
    fwd_range<false>(LO1, t1lo, 2051, LO2, t2lo, t2hi);
    fwd_range<true >(LO1, t1lo, 2051, H2W, b0, b1);
    __syncthreads();
    fwd_range<false>(LO2, t2lo, 1029, LO3, t3lo, t3hi);
    fwd_range<true >(LO2, t2lo, 1029, H3W, a0, a1);
    __syncthreads();
    fwd_range<false>(LO3, t3lo, 518, L4W, w0, w1);
    fwd_range<true >(LO3, t3lo, 518, H4W, w0, w1);
    __syncthreads();

    // ---- inverse chains (to the 2051-equivalent level) ----
    inv_range<false>(L4W, w0, AW,  a0, a1);               // chain0: LO(L4)
    inv_range<true >(H4W, w0, A4W, a0, a1);               // chain4: HI(H4)
    inv_range<true >(H3W, a0, A3W, b0, b1);               // chain3: HI(H3)
    inv_range<true >(H2W, b0, P2W, p0, p1);               // P2 = HI(H2)
    __syncthreads();
    inv_range<false>(AW,  a0, BW,  b0, b1);
    inv_range<false>(A4W, a0, B4W, b0, b1);
    inv_range<false>(A3W, b0, P3W, p0, p1);               // P3
    __syncthreads();
    inv_range<false>(BW,  b0, P0W, p0, p1);               // P0
    inv_range<false>(B4W, b0, P4W, p0, p1);               // P4
    __syncthreads();

    // ---- final inverse level: s_j on the block's 256 rows ----
    for (int idx = threadIdx.x; idx < 5 * BROWS; idx += 256) {
        int j = idx / BROWS;
        int r = idx & (BROWS - 1);
        int l = l0 + r;
        int base = (l >> 1) - p0;
        int odd = l & 1;
        const float* Pj = (j == 0) ? P0W : (j == 1) ? HI1 :
                          (j == 2) ? P2W : (j == 3) ? P3W : P4W;
        bool hi = (j == 1);
        float f0 = odd ? (hi ? c_DH[0] : c_DL[0]) : (hi ? c_DH[1] : c_DL[1]);
        float f1 = odd ? (hi ? c_DH[2] : c_DL[2]) : (hi ? c_DH[3] : c_DL[3]);
        float f2 = odd ? (hi ? c_DH[4] : c_DL[4]) : (hi ? c_DH[5] : c_DL[5]);
        float f3 = odd ? (hi ? c_DH[6] : c_DL[6]) : (hi ? c_DH[7] : c_DL[7]);
        float acc = Pj[base] * f0;
        acc = fmaf(Pj[base + 1], f1, acc);
        acc = fmaf(Pj[base + 2], f2, acc);
        acc = fmaf(Pj[base + 3], f3, acc);
        SJ[idx] = acc;
    }
    __syncthreads();

    // ---- rank-5 expansion, nontemporal stores ----
    int half = threadIdx.x >> 7;       // which row of each pair
    int c4 = threadIdx.x & 127;        // float4 index over 512 channels
    f32x4 g0 = ((const f32x4*)(GL + 0 * DM))[c4];
    f32x4 g1 = ((const f32x4*)(GL + 1 * DM))[c4];
    f32x4 g2 = ((const f32x4*)(GL + 2 * DM))[c4];
    f32x4 g3 = ((const f32x4*)(GL + 3 * DM))[c4];
    f32x4 g4 = ((const f32x4*)(GL + 4 * DM))[c4];

    size_t rowbase = (size_t)b * LSEQ + l0;
#pragma unroll 4
    for (int r = 0; r < BROWS / 2; ++r) {
        int rr = r * 2 + half;
        float s0 = SJ[rr];
        float s1 = SJ[BROWS + rr];
        float s2 = SJ[2 * BROWS + rr];
        float s3 = SJ[3 * BROWS + rr];
        float s4 = SJ[4 * BROWS + rr];
        f32x4 acc;
        acc.x = fmaf(s4, g4.x, fmaf(s3, g3.x, fmaf(s2, g2.x, fmaf(s1, g1.x, s0 * g0.x))));
        acc.y = fmaf(s4, g4.y, fmaf(s3, g3.y, fmaf(s2, g2.y, fmaf(s1, g1.y, s0 * g0.y))));
        acc.z = fmaf(s4, g4.z, fmaf(s3, g3.z, fmaf(s2, g2.z, fmaf(s1, g1.z, s0 * g0.z))));
        acc.w = fmaf(s4, g4.w, fmaf(s3, g3.w, fmaf(s2, g2.w, fmaf(s1, g1.w, s0 * g0.w))));
        __builtin_nontemporal_store(acc, (f32x4*)out + (rowbase + rr) * (DM / 4) + c4);
    }
}

extern "C" void kernel_launch(void* const* d_in, const int* in_sizes, int n_in,
                              void* d_out, int out_size, void* d_ws, size_t ws_size,
                              hipStream_t stream) {
    const float* x         = (const float*)d_in[0];
    const float* proj_w    = (const float*)d_in[1];
    const float* proj_b    = (const float*)d_in[2];
    const float* scale_emb = (const float*)d_in[3];
    const float* gate_w    = (const float*)d_in[4];
    const float* gate_b    = (const float*)d_in[5];
    float* out   = (float*)d_out;
    float* gates = (float*)d_ws;     // 5*512 floats

    gates_kernel<<<32, 1024, 0, stream>>>(scale_emb, gate_w, gate_b, gates);
    fused_kernel<<<NBLK, 256, 0, stream>>>(x, proj_w, proj_b, gates, out);
}